// Round 6
// baseline (647.608 us; speedup 1.0000x reference)
//
#include <hip/hip_runtime.h>
#include <hip/hip_bf16.h>

#define N_NODES 100000
#define N_EDGES 1600000
#define NEG_SLOPE 0.2f
#define LDS_STRIDE 132

typedef __attribute__((ext_vector_type(8))) short short8;
typedef __attribute__((ext_vector_type(4))) short short4v;
typedef __attribute__((ext_vector_type(4))) float floatx4;

__device__ inline short f2bf(float f) {
    __hip_bfloat16 h = __float2bfloat16(f);
    return *reinterpret_cast<short*>(&h);
}
__device__ inline float bf2f(unsigned short u) {
    union { unsigned int i; float f; } z; z.i = ((unsigned int)u) << 16; return z.f;
}

// ---------------- precompute M1[16][8], M2[16] ----------------
__global__ void k_pre(const float* __restrict__ We1, const float* __restrict__ attE1,
                      const float* __restrict__ We2, const float* __restrict__ attE2,
                      float* __restrict__ M1, float* __restrict__ M2) {
    int t = threadIdx.x;
    if (t < 128) {
        int d = t >> 3, h = t & 7;
        float s = 0.f;
        for (int c = 0; c < 16; ++c) s += We1[d * 128 + h * 16 + c] * attE1[h * 16 + c];
        M1[d * 8 + h] = s;   // layout [d][h]
    } else if (t < 144) {
        int d = t - 128;
        float s = 0.f;
        for (int c = 0; c < 16; ++c) s += We2[d * 16 + c] * attE2[c];
        M2[d] = s;
    }
}

// ---------------- GEMM1 via bf16 MFMA: xh1b (bf16) + a1s/a1d (fp32) ----------------
__global__ __launch_bounds__(256) void k_gemm1(
    const float* __restrict__ x, const float* __restrict__ W1,
    const float* __restrict__ attS, const float* __restrict__ attD,
    __hip_bfloat16* __restrict__ xh1b, float* __restrict__ a1s, float* __restrict__ a1d) {
    __shared__ short lds[128 * LDS_STRIDE];   // W1^T bf16 [n][k], later reused for out-tile
    int t = threadIdx.x;
    for (int i = t * 4; i < 16384; i += 1024) {
        float4 v = *(const float4*)(W1 + i);
        int k = i >> 7, n = i & 127;
        lds[(n + 0) * LDS_STRIDE + k] = f2bf(v.x);
        lds[(n + 1) * LDS_STRIDE + k] = f2bf(v.y);
        lds[(n + 2) * LDS_STRIDE + k] = f2bf(v.z);
        lds[(n + 3) * LDS_STRIDE + k] = f2bf(v.w);
    }
    __syncthreads();
    int w = t >> 6, l = t & 63;
    int q = l >> 4, m = l & 15;
    int row = blockIdx.x * 64 + w * 16 + m;
    int rowc = row < N_NODES ? row : 0;
    floatx4 acc[8];
#pragma unroll
    for (int nt = 0; nt < 8; ++nt) acc[nt] = (floatx4){0.f, 0.f, 0.f, 0.f};
#pragma unroll
    for (int KK = 0; KK < 4; ++KK) {
        int k0 = KK * 32 + q * 8;
        float4 alo = *(const float4*)(x + (size_t)rowc * 128 + k0);
        float4 ahi = *(const float4*)(x + (size_t)rowc * 128 + k0 + 4);
        short8 a = {f2bf(alo.x), f2bf(alo.y), f2bf(alo.z), f2bf(alo.w),
                    f2bf(ahi.x), f2bf(ahi.y), f2bf(ahi.z), f2bf(ahi.w)};
#pragma unroll
        for (int nt = 0; nt < 8; ++nt) {
            const short* bp = &lds[(nt * 16 + m) * LDS_STRIDE + k0];
            short4v blo = *(const short4v*)bp;
            short4v bhi = *(const short4v*)(bp + 4);
            short8 b = {blo.x, blo.y, blo.z, blo.w, bhi.x, bhi.y, bhi.z, bhi.w};
            acc[nt] = __builtin_amdgcn_mfma_f32_16x16x32_bf16(a, b, acc[nt], 0, 0, 0);
        }
    }
    int rb = blockIdx.x * 64 + w * 16 + q * 4;
#pragma unroll
    for (int nt = 0; nt < 8; ++nt) {
        float aS = attS[nt * 16 + m], aD = attD[nt * 16 + m];
        float p0 = acc[nt][0] * aS, p1 = acc[nt][1] * aS, p2 = acc[nt][2] * aS, p3 = acc[nt][3] * aS;
        float d0 = acc[nt][0] * aD, d1 = acc[nt][1] * aD, d2 = acc[nt][2] * aD, d3 = acc[nt][3] * aD;
        for (int dd = 1; dd < 16; dd <<= 1) {
            p0 += __shfl_xor(p0, dd); p1 += __shfl_xor(p1, dd);
            p2 += __shfl_xor(p2, dd); p3 += __shfl_xor(p3, dd);
            d0 += __shfl_xor(d0, dd); d1 += __shfl_xor(d1, dd);
            d2 += __shfl_xor(d2, dd); d3 += __shfl_xor(d3, dd);
        }
        if (m == 0) {
            if (rb + 0 < N_NODES) { a1s[(size_t)(rb+0)*8+nt] = p0; a1d[(size_t)(rb+0)*8+nt] = d0; }
            if (rb + 1 < N_NODES) { a1s[(size_t)(rb+1)*8+nt] = p1; a1d[(size_t)(rb+1)*8+nt] = d1; }
            if (rb + 2 < N_NODES) { a1s[(size_t)(rb+2)*8+nt] = p2; a1d[(size_t)(rb+2)*8+nt] = d2; }
            if (rb + 3 < N_NODES) { a1s[(size_t)(rb+3)*8+nt] = p3; a1d[(size_t)(rb+3)*8+nt] = d3; }
        }
    }
    __syncthreads();
#pragma unroll
    for (int nt = 0; nt < 8; ++nt) {
#pragma unroll
        for (int r = 0; r < 4; ++r)
            lds[(w * 16 + q * 4 + r) * LDS_STRIDE + nt * 16 + m] = f2bf(acc[nt][r]);
    }
    __syncthreads();
    int r2 = t >> 2, c2 = (t & 3) * 32;
    int gr = blockIdx.x * 64 + r2;
    if (gr < N_NODES) {
        short* gp = (short*)(xh1b + (size_t)gr * 128 + c2);
#pragma unroll
        for (int i = 0; i < 8; ++i)
            *(short4v*)(gp + i * 4) = *(const short4v*)&lds[r2 * LDS_STRIDE + c2 + i * 4];
    }
}

// ---------------- CSR build ----------------
__global__ void k_hist(const int* __restrict__ dst, int* __restrict__ count) {
    int i = blockIdx.x * blockDim.x + threadIdx.x;
    if (i < N_EDGES) atomicAdd(&count[dst[i]], 1);
}

__global__ __launch_bounds__(256) void k_scan1(const int* __restrict__ count,
                                               int* __restrict__ offs, int* __restrict__ partials) {
    __shared__ int s[256];
    int t = threadIdx.x;
    int i = blockIdx.x * 256 + t;
    int v = (i < N_NODES) ? count[i] : 0;
    s[t] = v; __syncthreads();
    for (int off = 1; off < 256; off <<= 1) {
        int add = (t >= off) ? s[t - off] : 0;
        __syncthreads();
        s[t] += add; __syncthreads();
    }
    if (i < N_NODES) offs[i] = s[t] - v;
    if (t == 255) partials[blockIdx.x] = s[255];
}

__global__ __launch_bounds__(512) void k_scan2(int* __restrict__ partials, int nb) {
    __shared__ int s[512];
    int t = threadIdx.x;
    int v = (t < nb) ? partials[t] : 0;
    s[t] = v; __syncthreads();
    for (int off = 1; off < 512; off <<= 1) {
        int add = (t >= off) ? s[t - off] : 0;
        __syncthreads();
        s[t] += add; __syncthreads();
    }
    if (t < nb) partials[t] = s[t] - v;
}

__global__ void k_scan3(int* __restrict__ offs, const int* __restrict__ partials) {
    int i = blockIdx.x * 256 + threadIdx.x;
    if (i < N_NODES) offs[i] += partials[blockIdx.x];
}

// ---------------- k_scatter: {e, src[e]} 8-byte permutation scatter ----------------
__global__ __launch_bounds__(256) void k_scatter(
    const int* __restrict__ src, const int* __restrict__ dst, const int* __restrict__ offs,
    int* __restrict__ cursor, int2* __restrict__ pes) {
    int e = blockIdx.x * 256 + threadIdx.x;
    int d = dst[e];
    int s = src[e];
    int p = offs[d] + atomicAdd(&cursor[d], 1);
    int2 v; v.x = e; v.y = s;
    pes[p] = v;
}

// ---------------- k_fill: dstc[p] = owning node (CSR segment id) ----------------
__global__ __launch_bounds__(256) void k_fill(
    const int* __restrict__ offs, const int* __restrict__ count, int* __restrict__ dstc) {
    int n = blockIdx.x * 256 + threadIdx.x;
    if (n >= N_NODES) return;
    int s = offs[n], e = s + count[n];
    for (int i = s; i < e; ++i) dstc[i] = n;
}

// ---------------- k_attn: CSR-order; only random access is the ea line gather ----------------
__global__ __launch_bounds__(256) void k_attn(
    const int2* __restrict__ pes, const int* __restrict__ dstc,
    const float* __restrict__ ea, const float* __restrict__ M1, const float* __restrict__ M2,
    const float* __restrict__ a1s, const float* __restrict__ a1d,
    float* __restrict__ ew1c, float* __restrict__ ae2c, int* __restrict__ srcc) {
    __shared__ float M1s[128], M2s[16];
    int t = threadIdx.x;
    if (t < 128) M1s[t] = M1[t];
    if (t >= 128 && t < 144) M2s[t - 128] = M2[t - 128];
    __syncthreads();
    int p = blockIdx.x * 256 + t;
    int2 es = pes[p];
    int e = es.x, s = es.y;
    int d = dstc[p];                      // near-uniform across adjacent lanes -> broadcast
    float eav[16];
#pragma unroll
    for (int qq = 0; qq < 4; ++qq) {
        float4 v = *(const float4*)(ea + (size_t)e * 16 + qq * 4);
        eav[qq * 4] = v.x; eav[qq * 4 + 1] = v.y; eav[qq * 4 + 2] = v.z; eav[qq * 4 + 3] = v.w;
    }
    float ae1[8];
#pragma unroll
    for (int h = 0; h < 8; ++h) ae1[h] = 0.f;
#pragma unroll
    for (int dd = 0; dd < 16; ++dd) {
#pragma unroll
        for (int h = 0; h < 8; ++h) ae1[h] += eav[dd] * M1s[dd * 8 + h];
    }
    float aes = 0.f;
#pragma unroll
    for (int dd = 0; dd < 16; ++dd) aes += eav[dd] * M2s[dd];
    float4 s0 = *(const float4*)(a1s + (size_t)s * 8);
    float4 s1 = *(const float4*)(a1s + (size_t)s * 8 + 4);
    float4 d0 = *(const float4*)(a1d + (size_t)d * 8);
    float4 d1 = *(const float4*)(a1d + (size_t)d * 8 + 4);
    float as_[8] = {s0.x, s0.y, s0.z, s0.w, s1.x, s1.y, s1.z, s1.w};
    float ad_[8] = {d0.x, d0.y, d0.z, d0.w, d1.x, d1.y, d1.z, d1.w};
    float ew[8];
#pragma unroll
    for (int h = 0; h < 8; ++h) {
        float v = as_[h] + ad_[h] + ae1[h];
        v = v > 0.f ? v : NEG_SLOPE * v;
        ew[h] = __expf(v);
    }
    float4 w0 = {ew[0], ew[1], ew[2], ew[3]};
    float4 w1 = {ew[4], ew[5], ew[6], ew[7]};
    *(float4*)(ew1c + (size_t)p * 8) = w0;
    *(float4*)(ew1c + (size_t)p * 8 + 4) = w1;
    ae2c[p] = aes;
    srcc[p] = s;
}

// ---------------- layer-1 aggregation: 16 edge slots, 16B line-aligned gathers ----------------
// 256 threads: j = t&15 owns features [j*8, j*8+8) (16 B of bf16); k = t>>4 = edge slot.
// head of feature group = j>>1. Most nodes (deg<=16) finish the edge loop in ONE iteration.
__global__ __launch_bounds__(256) void k_agg1(
    const int* __restrict__ srcc, const float* __restrict__ ew1c,
    const __hip_bfloat16* __restrict__ xh1b, const int* __restrict__ offs,
    const int* __restrict__ count, const float* __restrict__ b1, float* __restrict__ h1) {
    __shared__ float sacc[3][16][8];
    __shared__ float sw[3][16];
    int n = blockIdx.x;
    int t = threadIdx.x;
    int j = t & 15, k = t >> 4;
    int start = offs[n], deg = count[n];
    float acc[8] = {0.f, 0.f, 0.f, 0.f, 0.f, 0.f, 0.f, 0.f};
    float wsum = 0.f;
    for (int i = k; i < deg; i += 16) {
        int p = start + i;
        int s = srcc[p];
        float w = ew1c[(size_t)p * 8 + (j >> 1)];
        uint4 xv = *(const uint4*)((const char*)xh1b + (size_t)s * 256 + j * 16);
        acc[0] += w * bf2f((unsigned short)(xv.x & 0xffff));
        acc[1] += w * bf2f((unsigned short)(xv.x >> 16));
        acc[2] += w * bf2f((unsigned short)(xv.y & 0xffff));
        acc[3] += w * bf2f((unsigned short)(xv.y >> 16));
        acc[4] += w * bf2f((unsigned short)(xv.z & 0xffff));
        acc[5] += w * bf2f((unsigned short)(xv.z >> 16));
        acc[6] += w * bf2f((unsigned short)(xv.w & 0xffff));
        acc[7] += w * bf2f((unsigned short)(xv.w >> 16));
        wsum += w;
    }
    // combine 4 slots within each wave (slots differ in lane bits 4,5)
#pragma unroll
    for (int u = 0; u < 8; ++u) {
        acc[u] += __shfl_xor(acc[u], 16);
        acc[u] += __shfl_xor(acc[u], 32);
    }
    wsum += __shfl_xor(wsum, 16);
    wsum += __shfl_xor(wsum, 32);
    int wv = t >> 6, lane = t & 63;
    if (wv > 0 && lane < 16) {
#pragma unroll
        for (int u = 0; u < 8; ++u) sacc[wv - 1][j][u] = acc[u];
        sw[wv - 1][j] = wsum;
    }
    __syncthreads();
    if (t < 16) {
#pragma unroll
        for (int w2 = 0; w2 < 3; ++w2) {
#pragma unroll
            for (int u = 0; u < 8; ++u) acc[u] += sacc[w2][j][u];
            wsum += sw[w2][j];
        }
        float inv = 1.f / (wsum + 1e-16f);
        float4 blo = *(const float4*)(b1 + j * 8);
        float4 bhi = *(const float4*)(b1 + j * 8 + 4);
        float o[8];
        o[0] = acc[0] * inv + blo.x; o[1] = acc[1] * inv + blo.y;
        o[2] = acc[2] * inv + blo.z; o[3] = acc[3] * inv + blo.w;
        o[4] = acc[4] * inv + bhi.x; o[5] = acc[5] * inv + bhi.y;
        o[6] = acc[6] * inv + bhi.z; o[7] = acc[7] * inv + bhi.w;
#pragma unroll
        for (int u = 0; u < 8; ++u) o[u] = o[u] > 0.f ? o[u] : __expf(o[u]) - 1.f;
        float4 r0 = {o[0], o[1], o[2], o[3]};
        float4 r1 = {o[4], o[5], o[6], o[7]};
        *(float4*)(h1 + (size_t)n * 128 + j * 8) = r0;
        *(float4*)(h1 + (size_t)n * 128 + j * 8 + 4) = r1;
    }
}

// ---------------- GEMM2: xh2 = h1 @ W2, plus a2s/a2d ----------------
__global__ __launch_bounds__(256) void k_gemm2(
    const float* __restrict__ h1, const float* __restrict__ W2,
    const float* __restrict__ attS, const float* __restrict__ attD,
    float* __restrict__ xh2, float* __restrict__ a2s, float* __restrict__ a2d) {
    __shared__ float W2s[128 * 16];
    __shared__ float hs[16 * 132];
    int t = threadIdx.x;
    for (int i = t * 4; i < 2048; i += 1024)
        *(float4*)(W2s + i) = *(const float4*)(W2 + i);
    size_t base = (size_t)blockIdx.x * 16 * 128;
    for (int i = t * 4; i < 2048; i += 1024) {
        float4 v = *(const float4*)(h1 + base + i);
        int r = i >> 7, k = i & 127;
        float* dstp = hs + r * 132 + k;
        dstp[0] = v.x; dstp[1] = v.y; dstp[2] = v.z; dstp[3] = v.w;
    }
    __syncthreads();
    int r = t >> 4, c = t & 15;
    float acc = 0.f;
#pragma unroll 4
    for (int k = 0; k < 128; ++k) acc += hs[r * 132 + k] * W2s[k * 16 + c];
    int row = blockIdx.x * 16 + r;
    xh2[(size_t)row * 16 + c] = acc;
    float ps = acc * attS[c], pd = acc * attD[c];
#pragma unroll
    for (int m = 1; m < 16; m <<= 1) { ps += __shfl_xor(ps, m); pd += __shfl_xor(pd, m); }
    if (c == 0) { a2s[row] = ps; a2d[row] = pd; }
}

// ---------------- layer-2 aggregation + bias + log_softmax ----------------
__global__ __launch_bounds__(64) void k_agg2(
    const int* __restrict__ srcc, const float* __restrict__ ae2c,
    const float* __restrict__ a2s, const float* __restrict__ a2d, const float* __restrict__ xh2,
    const int* __restrict__ offs, const int* __restrict__ count,
    const float* __restrict__ b2, float* __restrict__ out) {
    int n = blockIdx.x;
    int t = threadIdx.x;
    int l = t & 3, k = t >> 2;
    int start = offs[n], deg = count[n];
    float ad = a2d[n];
    float4 acc = {0.f, 0.f, 0.f, 0.f};
    float wsum = 0.f;
    for (int i = k; i < deg; i += 16) {
        int p = start + i;
        int s = srcc[p];
        float lg = a2s[s] + ad + ae2c[p];
        lg = lg > 0.f ? lg : NEG_SLOPE * lg;
        float w = __expf(lg);
        float4 xv = *(const float4*)(xh2 + (size_t)s * 16 + l * 4);
        acc.x += w * xv.x; acc.y += w * xv.y; acc.z += w * xv.z; acc.w += w * xv.w;
        wsum += w;
    }
#pragma unroll
    for (int m = 4; m < 64; m <<= 1) {
        acc.x += __shfl_xor(acc.x, m); acc.y += __shfl_xor(acc.y, m);
        acc.z += __shfl_xor(acc.z, m); acc.w += __shfl_xor(acc.w, m);
        wsum += __shfl_xor(wsum, m);
    }
    float inv = 1.f / (wsum + 1e-16f);
    float4 b = *(const float4*)(b2 + l * 4);
    float4 lo;
    lo.x = acc.x * inv + b.x; lo.y = acc.y * inv + b.y;
    lo.z = acc.z * inv + b.z; lo.w = acc.w * inv + b.w;
    float mx = fmaxf(fmaxf(lo.x, lo.y), fmaxf(lo.z, lo.w));
    mx = fmaxf(mx, __shfl_xor(mx, 1)); mx = fmaxf(mx, __shfl_xor(mx, 2));
    float ex = __expf(lo.x - mx) + __expf(lo.y - mx) + __expf(lo.z - mx) + __expf(lo.w - mx);
    ex += __shfl_xor(ex, 1); ex += __shfl_xor(ex, 2);
    float ls = mx + __logf(ex);
    if (t < 4) {
        float4 r = {lo.x - ls, lo.y - ls, lo.z - ls, lo.w - ls};
        *(float4*)(out + (size_t)n * 16 + l * 4) = r;
    }
}

extern "C" void kernel_launch(void* const* d_in, const int* in_sizes, int n_in,
                              void* d_out, int out_size, void* d_ws, size_t ws_size,
                              hipStream_t stream) {
    const float* x     = (const float*)d_in[0];
    const int*   ei    = (const int*)d_in[1];
    const float* ea    = (const float*)d_in[2];
    const float* W1    = (const float*)d_in[3];
    const float* attS1 = (const float*)d_in[4];
    const float* attD1 = (const float*)d_in[5];
    const float* We1   = (const float*)d_in[6];
    const float* attE1 = (const float*)d_in[7];
    const float* b1    = (const float*)d_in[8];
    const float* W2    = (const float*)d_in[9];
    const float* attS2 = (const float*)d_in[10];
    const float* attD2 = (const float*)d_in[11];
    const float* We2   = (const float*)d_in[12];
    const float* attE2 = (const float*)d_in[13];
    const float* b2    = (const float*)d_in[14];
    float* out = (float*)d_out;
    const int* src = ei;
    const int* dst = ei + N_EDGES;

    char* p = (char*)d_ws;
    auto alloc = [&](size_t bytes) { char* r = p; p += (bytes + 255) & ~(size_t)255; return r; };
    __hip_bfloat16* xh1b = (__hip_bfloat16*)alloc((size_t)N_NODES * 128 * 2);  // 25.6 MB
    float* h1       = (float*)alloc((size_t)N_NODES * 128 * 4);                // 51.2 MB
    float* ew1c     = (float*)alloc((size_t)N_EDGES * 8 * 4);                  // 51.2 MB
    float* ae2c     = (float*)alloc((size_t)N_EDGES * 4);                      // 6.4 MB
    int*   srcc     = (int*)alloc((size_t)N_EDGES * 4);                        // 6.4 MB
    int2*  pes      = (int2*)alloc((size_t)N_EDGES * 8);                       // 12.8 MB
    int*   dstc     = (int*)alloc((size_t)N_EDGES * 4);                        // 6.4 MB
    float* xh2      = (float*)alloc((size_t)N_NODES * 16 * 4);                 // 6.4 MB
    float* a2s      = (float*)alloc((size_t)N_NODES * 4);
    float* a2d      = (float*)alloc((size_t)N_NODES * 4);
    float* a1s      = (float*)alloc((size_t)N_NODES * 8 * 4);
    float* a1d      = (float*)alloc((size_t)N_NODES * 8 * 4);
    int*   count    = (int*)alloc((size_t)N_NODES * 4);
    int*   cursor   = (int*)alloc((size_t)N_NODES * 4);   // contiguous after count
    int*   offs     = (int*)alloc((size_t)(N_NODES + 1) * 4);
    int*   partials = (int*)alloc(1024 * 4);
    float* M1       = (float*)alloc(128 * 4);
    float* M2       = (float*)alloc(64 * 4);
    if ((size_t)(p - (char*)d_ws) > ws_size) return;  // workspace too small — fail visibly

    const int nb_scan = (N_NODES + 255) / 256;  // 391

    hipMemsetAsync(count, 0, (size_t)2 * N_NODES * 4 + 256, stream);  // count + cursor
    k_pre<<<1, 192, 0, stream>>>(We1, attE1, We2, attE2, M1, M2);
    k_gemm1<<<(N_NODES + 63) / 64, 256, 0, stream>>>(x, W1, attS1, attD1, xh1b, a1s, a1d);
    k_hist<<<(N_EDGES + 255) / 256, 256, 0, stream>>>(dst, count);
    k_scan1<<<nb_scan, 256, 0, stream>>>(count, offs, partials);
    k_scan2<<<1, 512, 0, stream>>>(partials, nb_scan);
    k_scan3<<<nb_scan, 256, 0, stream>>>(offs, partials);
    k_scatter<<<N_EDGES / 256, 256, 0, stream>>>(src, dst, offs, cursor, pes);
    k_fill<<<nb_scan, 256, 0, stream>>>(offs, count, dstc);
    k_attn<<<N_EDGES / 256, 256, 0, stream>>>(pes, dstc, ea, M1, M2, a1s, a1d,
                                              ew1c, ae2c, srcc);
    k_agg1<<<N_NODES, 256, 0, stream>>>(srcc, ew1c, xh1b, offs, count, b1, h1);
    k_gemm2<<<N_NODES / 16, 256, 0, stream>>>(h1, W2, attS2, attD2, xh2, a2s, a2d);
    k_agg2<<<N_NODES, 64, 0, stream>>>(srcc, ae2c, a2s, a2d, xh2, offs, count, b2, out);
}

// Round 7
// 614.913 us; speedup vs baseline: 1.0532x; 1.0532x over previous
//
#include <hip/hip_runtime.h>
#include <hip/hip_bf16.h>

#define N_NODES 100000
#define N_EDGES 1600000
#define NEG_SLOPE 0.2f
#define LDS_STRIDE 132

typedef __attribute__((ext_vector_type(8))) short short8;
typedef __attribute__((ext_vector_type(4))) short short4v;
typedef __attribute__((ext_vector_type(4))) float floatx4;

__device__ inline short f2bf(float f) {
    __hip_bfloat16 h = __float2bfloat16(f);
    return *reinterpret_cast<short*>(&h);
}
__device__ inline float bf2f(unsigned short u) {
    union { unsigned int i; float f; } z; z.i = ((unsigned int)u) << 16; return z.f;
}

// ---------------- precompute M1[16][8], M2[16] ----------------
__global__ void k_pre(const float* __restrict__ We1, const float* __restrict__ attE1,
                      const float* __restrict__ We2, const float* __restrict__ attE2,
                      float* __restrict__ M1, float* __restrict__ M2) {
    int t = threadIdx.x;
    if (t < 128) {
        int d = t >> 3, h = t & 7;
        float s = 0.f;
        for (int c = 0; c < 16; ++c) s += We1[d * 128 + h * 16 + c] * attE1[h * 16 + c];
        M1[d * 8 + h] = s;   // layout [d][h]
    } else if (t < 144) {
        int d = t - 128;
        float s = 0.f;
        for (int c = 0; c < 16; ++c) s += We2[d * 16 + c] * attE2[c];
        M2[d] = s;
    }
}

// ---------------- GEMM1 via bf16 MFMA: 128 rows/block, packed staging ----------------
__global__ __launch_bounds__(256) void k_gemm1(
    const float* __restrict__ x, const float* __restrict__ W1,
    const float* __restrict__ attS, const float* __restrict__ attD,
    __hip_bfloat16* __restrict__ xh1b, float* __restrict__ a1s, float* __restrict__ a1d) {
    __shared__ short ldsW[128 * LDS_STRIDE];   // W1^T bf16 [n][k]
    __shared__ short ldsO[64 * LDS_STRIDE];    // out-tile staging
    int t = threadIdx.x;
    unsigned int* ldsW32 = (unsigned int*)ldsW;
    for (int u = t; u < 2048; u += 256) {
        int kp = u >> 5;            // k-pair 0..63
        int n4 = (u & 31) * 4;
        float4 a = *(const float4*)(W1 + (size_t)(2 * kp) * 128 + n4);
        float4 b = *(const float4*)(W1 + (size_t)(2 * kp + 1) * 128 + n4);
        ldsW32[(n4 + 0) * 66 + kp] =
            (unsigned int)(unsigned short)f2bf(a.x) | ((unsigned int)(unsigned short)f2bf(b.x) << 16);
        ldsW32[(n4 + 1) * 66 + kp] =
            (unsigned int)(unsigned short)f2bf(a.y) | ((unsigned int)(unsigned short)f2bf(b.y) << 16);
        ldsW32[(n4 + 2) * 66 + kp] =
            (unsigned int)(unsigned short)f2bf(a.z) | ((unsigned int)(unsigned short)f2bf(b.z) << 16);
        ldsW32[(n4 + 3) * 66 + kp] =
            (unsigned int)(unsigned short)f2bf(a.w) | ((unsigned int)(unsigned short)f2bf(b.w) << 16);
    }
    __syncthreads();
    int w = t >> 6, l = t & 63;
    int q = l >> 4, m = l & 15;
#pragma unroll
    for (int rt = 0; rt < 2; ++rt) {
        int row = blockIdx.x * 128 + rt * 64 + w * 16 + m;
        int rowc = row < N_NODES ? row : 0;
        floatx4 acc[8];
#pragma unroll
        for (int nt = 0; nt < 8; ++nt) acc[nt] = (floatx4){0.f, 0.f, 0.f, 0.f};
#pragma unroll
        for (int KK = 0; KK < 4; ++KK) {
            int k0 = KK * 32 + q * 8;
            float4 alo = *(const float4*)(x + (size_t)rowc * 128 + k0);
            float4 ahi = *(const float4*)(x + (size_t)rowc * 128 + k0 + 4);
            short8 a = {f2bf(alo.x), f2bf(alo.y), f2bf(alo.z), f2bf(alo.w),
                        f2bf(ahi.x), f2bf(ahi.y), f2bf(ahi.z), f2bf(ahi.w)};
#pragma unroll
            for (int nt = 0; nt < 8; ++nt) {
                const short* bp = &ldsW[(nt * 16 + m) * LDS_STRIDE + k0];
                short4v blo = *(const short4v*)bp;
                short4v bhi = *(const short4v*)(bp + 4);
                short8 b = {blo.x, blo.y, blo.z, blo.w, bhi.x, bhi.y, bhi.z, bhi.w};
                acc[nt] = __builtin_amdgcn_mfma_f32_16x16x32_bf16(a, b, acc[nt], 0, 0, 0);
            }
        }
        int rb = blockIdx.x * 128 + rt * 64 + w * 16 + q * 4;
#pragma unroll
        for (int nt = 0; nt < 8; ++nt) {
            float aS = attS[nt * 16 + m], aD = attD[nt * 16 + m];
            float p0 = acc[nt][0] * aS, p1 = acc[nt][1] * aS, p2 = acc[nt][2] * aS, p3 = acc[nt][3] * aS;
            float d0 = acc[nt][0] * aD, d1 = acc[nt][1] * aD, d2 = acc[nt][2] * aD, d3 = acc[nt][3] * aD;
            for (int dd = 1; dd < 16; dd <<= 1) {
                p0 += __shfl_xor(p0, dd); p1 += __shfl_xor(p1, dd);
                p2 += __shfl_xor(p2, dd); p3 += __shfl_xor(p3, dd);
                d0 += __shfl_xor(d0, dd); d1 += __shfl_xor(d1, dd);
                d2 += __shfl_xor(d2, dd); d3 += __shfl_xor(d3, dd);
            }
            if (m == 0) {
                if (rb + 0 < N_NODES) { a1s[(size_t)(rb+0)*8+nt] = p0; a1d[(size_t)(rb+0)*8+nt] = d0; }
                if (rb + 1 < N_NODES) { a1s[(size_t)(rb+1)*8+nt] = p1; a1d[(size_t)(rb+1)*8+nt] = d1; }
                if (rb + 2 < N_NODES) { a1s[(size_t)(rb+2)*8+nt] = p2; a1d[(size_t)(rb+2)*8+nt] = d2; }
                if (rb + 3 < N_NODES) { a1s[(size_t)(rb+3)*8+nt] = p3; a1d[(size_t)(rb+3)*8+nt] = d3; }
            }
        }
#pragma unroll
        for (int nt = 0; nt < 8; ++nt) {
#pragma unroll
            for (int r = 0; r < 4; ++r)
                ldsO[(w * 16 + q * 4 + r) * LDS_STRIDE + nt * 16 + m] = f2bf(acc[nt][r]);
        }
        __syncthreads();
        int r2 = t >> 2, c2 = (t & 3) * 32;
        int gr = blockIdx.x * 128 + rt * 64 + r2;
        if (gr < N_NODES) {
            short* gp = (short*)(xh1b + (size_t)gr * 128 + c2);
#pragma unroll
            for (int i = 0; i < 8; ++i)
                *(short4v*)(gp + i * 4) = *(const short4v*)&ldsO[r2 * LDS_STRIDE + c2 + i * 4];
        }
        __syncthreads();
    }
}

// ---------------- CSR build ----------------
__global__ void k_hist(const int* __restrict__ dst, int* __restrict__ count) {
    int i = blockIdx.x * blockDim.x + threadIdx.x;
    if (i < N_EDGES) atomicAdd(&count[dst[i]], 1);
}

__global__ __launch_bounds__(256) void k_scan1(const int* __restrict__ count,
                                               int* __restrict__ offs, int* __restrict__ partials) {
    __shared__ int s[256];
    int t = threadIdx.x;
    int i = blockIdx.x * 256 + t;
    int v = (i < N_NODES) ? count[i] : 0;
    s[t] = v; __syncthreads();
    for (int off = 1; off < 256; off <<= 1) {
        int add = (t >= off) ? s[t - off] : 0;
        __syncthreads();
        s[t] += add; __syncthreads();
    }
    if (i < N_NODES) offs[i] = s[t] - v;
    if (t == 255) partials[blockIdx.x] = s[255];
}

__global__ __launch_bounds__(512) void k_scan2(int* __restrict__ partials, int nb) {
    __shared__ int s[512];
    int t = threadIdx.x;
    int v = (t < nb) ? partials[t] : 0;
    s[t] = v; __syncthreads();
    for (int off = 1; off < 512; off <<= 1) {
        int add = (t >= off) ? s[t - off] : 0;
        __syncthreads();
        s[t] += add; __syncthreads();
    }
    if (t < nb) partials[t] = s[t] - v;
}

__global__ void k_scan3(int* __restrict__ offs, const int* __restrict__ partials) {
    int i = blockIdx.x * 256 + threadIdx.x;
    if (i < N_NODES) offs[i] += partials[blockIdx.x];
}

// ---------------- k_scatter: {e, src, dst} 16-byte permutation scatter ----------------
__global__ __launch_bounds__(256) void k_scatter(
    const int* __restrict__ src, const int* __restrict__ dst, const int* __restrict__ offs,
    int* __restrict__ cursor, int4* __restrict__ pes) {
    int e = blockIdx.x * 256 + threadIdx.x;
    int d = dst[e];
    int s = src[e];
    int p = offs[d] + atomicAdd(&cursor[d], 1);
    int4 v; v.x = e; v.y = s; v.z = d; v.w = 0;
    pes[p] = v;
}

// ---------------- k_attn: CSR-order; only random access is the ea line gather ----------------
__global__ __launch_bounds__(256) void k_attn(
    const int4* __restrict__ pes,
    const float* __restrict__ ea, const float* __restrict__ M1, const float* __restrict__ M2,
    const float* __restrict__ a1s, const float* __restrict__ a1d,
    float* __restrict__ ew1c, float* __restrict__ ae2c, int* __restrict__ srcc) {
    __shared__ float M1s[128], M2s[16];
    int t = threadIdx.x;
    if (t < 128) M1s[t] = M1[t];
    if (t >= 128 && t < 144) M2s[t - 128] = M2[t - 128];
    __syncthreads();
    int p = blockIdx.x * 256 + t;
    int4 es = pes[p];
    int e = es.x, s = es.y, d = es.z;   // d near-uniform across adjacent lanes -> broadcast
    float eav[16];
#pragma unroll
    for (int qq = 0; qq < 4; ++qq) {
        float4 v = *(const float4*)(ea + (size_t)e * 16 + qq * 4);
        eav[qq * 4] = v.x; eav[qq * 4 + 1] = v.y; eav[qq * 4 + 2] = v.z; eav[qq * 4 + 3] = v.w;
    }
    float ae1[8];
#pragma unroll
    for (int h = 0; h < 8; ++h) ae1[h] = 0.f;
#pragma unroll
    for (int dd = 0; dd < 16; ++dd) {
#pragma unroll
        for (int h = 0; h < 8; ++h) ae1[h] += eav[dd] * M1s[dd * 8 + h];
    }
    float aes = 0.f;
#pragma unroll
    for (int dd = 0; dd < 16; ++dd) aes += eav[dd] * M2s[dd];
    float4 s0 = *(const float4*)(a1s + (size_t)s * 8);
    float4 s1 = *(const float4*)(a1s + (size_t)s * 8 + 4);
    float4 d0 = *(const float4*)(a1d + (size_t)d * 8);
    float4 d1 = *(const float4*)(a1d + (size_t)d * 8 + 4);
    float as_[8] = {s0.x, s0.y, s0.z, s0.w, s1.x, s1.y, s1.z, s1.w};
    float ad_[8] = {d0.x, d0.y, d0.z, d0.w, d1.x, d1.y, d1.z, d1.w};
    float ew[8];
#pragma unroll
    for (int h = 0; h < 8; ++h) {
        float v = as_[h] + ad_[h] + ae1[h];
        v = v > 0.f ? v : NEG_SLOPE * v;
        ew[h] = __expf(v);
    }
    float4 w0 = {ew[0], ew[1], ew[2], ew[3]};
    float4 w1 = {ew[4], ew[5], ew[6], ew[7]};
    *(float4*)(ew1c + (size_t)p * 8) = w0;
    *(float4*)(ew1c + (size_t)p * 8 + 4) = w1;
    ae2c[p] = aes;
    srcc[p] = s;
}

// ---------------- layer-1 aggregation: R5 layout + 2-way unrolled gathers ----------------
// 128 threads: j = t&31 owns 4 features (head j>>2); k = t>>5 = 4 edge slots.
// Each iteration issues TWO independent xh1b row-gathers (edges i, i+4).
__global__ __launch_bounds__(128) void k_agg1(
    const int* __restrict__ srcc, const float* __restrict__ ew1c,
    const __hip_bfloat16* __restrict__ xh1b, const int* __restrict__ offs,
    const int* __restrict__ count, const float* __restrict__ b1, float* __restrict__ h1) {
    __shared__ float4 racc[32];
    __shared__ float rw[32];
    int n = blockIdx.x;
    int t = threadIdx.x;
    int j = t & 31, k = t >> 5;
    int hh = j >> 2;
    int start = offs[n], deg = count[n];
    float4 acc = {0.f, 0.f, 0.f, 0.f};
    float wsum = 0.f;
    for (int i = k; i < deg; i += 8) {
        int p0 = start + i;
        int s0 = srcc[p0];
        float w0 = ew1c[(size_t)p0 * 8 + hh];
        int i1 = i + 4;
        int s1 = 0; float w1 = 0.f;
        if (i1 < deg) {
            int p1 = start + i1;
            s1 = srcc[p1];
            w1 = ew1c[(size_t)p1 * 8 + hh];
        }
        uint2 xv0 = *(const uint2*)((const char*)xh1b + (size_t)s0 * 256 + j * 8);
        uint2 xv1 = *(const uint2*)((const char*)xh1b + (size_t)s1 * 256 + j * 8);
        acc.x += w0 * bf2f((unsigned short)(xv0.x & 0xffff));
        acc.y += w0 * bf2f((unsigned short)(xv0.x >> 16));
        acc.z += w0 * bf2f((unsigned short)(xv0.y & 0xffff));
        acc.w += w0 * bf2f((unsigned short)(xv0.y >> 16));
        acc.x += w1 * bf2f((unsigned short)(xv1.x & 0xffff));
        acc.y += w1 * bf2f((unsigned short)(xv1.x >> 16));
        acc.z += w1 * bf2f((unsigned short)(xv1.y & 0xffff));
        acc.w += w1 * bf2f((unsigned short)(xv1.y >> 16));
        wsum += w0 + w1;
    }
    acc.x += __shfl_xor(acc.x, 32); acc.y += __shfl_xor(acc.y, 32);
    acc.z += __shfl_xor(acc.z, 32); acc.w += __shfl_xor(acc.w, 32);
    wsum += __shfl_xor(wsum, 32);
    if (t >= 64 && t < 96) { racc[j] = acc; rw[j] = wsum; }
    __syncthreads();
    if (t < 32) {
        float4 o = racc[j];
        acc.x += o.x; acc.y += o.y; acc.z += o.z; acc.w += o.w;
        wsum += rw[j];
        float inv = 1.f / (wsum + 1e-16f);
        float4 b = *(const float4*)(b1 + j * 4);
        float4 r;
        r.x = acc.x * inv + b.x; r.y = acc.y * inv + b.y;
        r.z = acc.z * inv + b.z; r.w = acc.w * inv + b.w;
        r.x = r.x > 0.f ? r.x : __expf(r.x) - 1.f;
        r.y = r.y > 0.f ? r.y : __expf(r.y) - 1.f;
        r.z = r.z > 0.f ? r.z : __expf(r.z) - 1.f;
        r.w = r.w > 0.f ? r.w : __expf(r.w) - 1.f;
        *(float4*)(h1 + (size_t)n * 128 + j * 4) = r;
    }
}

// ---------------- GEMM2: xh2 = h1 @ W2, plus a2s/a2d ----------------
__global__ __launch_bounds__(256) void k_gemm2(
    const float* __restrict__ h1, const float* __restrict__ W2,
    const float* __restrict__ attS, const float* __restrict__ attD,
    float* __restrict__ xh2, float* __restrict__ a2s, float* __restrict__ a2d) {
    __shared__ float W2s[128 * 16];
    __shared__ float hs[16 * 132];
    int t = threadIdx.x;
    for (int i = t * 4; i < 2048; i += 1024)
        *(float4*)(W2s + i) = *(const float4*)(W2 + i);
    size_t base = (size_t)blockIdx.x * 16 * 128;
    for (int i = t * 4; i < 2048; i += 1024) {
        float4 v = *(const float4*)(h1 + base + i);
        int r = i >> 7, k = i & 127;
        float* dstp = hs + r * 132 + k;
        dstp[0] = v.x; dstp[1] = v.y; dstp[2] = v.z; dstp[3] = v.w;
    }
    __syncthreads();
    int r = t >> 4, c = t & 15;
    float acc = 0.f;
#pragma unroll 4
    for (int k = 0; k < 128; ++k) acc += hs[r * 132 + k] * W2s[k * 16 + c];
    int row = blockIdx.x * 16 + r;
    xh2[(size_t)row * 16 + c] = acc;
    float ps = acc * attS[c], pd = acc * attD[c];
#pragma unroll
    for (int m = 1; m < 16; m <<= 1) { ps += __shfl_xor(ps, m); pd += __shfl_xor(pd, m); }
    if (c == 0) { a2s[row] = ps; a2d[row] = pd; }
}

// ---------------- layer-2 aggregation + bias + log_softmax ----------------
__global__ __launch_bounds__(64) void k_agg2(
    const int* __restrict__ srcc, const float* __restrict__ ae2c,
    const float* __restrict__ a2s, const float* __restrict__ a2d, const float* __restrict__ xh2,
    const int* __restrict__ offs, const int* __restrict__ count,
    const float* __restrict__ b2, float* __restrict__ out) {
    int n = blockIdx.x;
    int t = threadIdx.x;
    int l = t & 3, k = t >> 2;
    int start = offs[n], deg = count[n];
    float ad = a2d[n];
    float4 acc = {0.f, 0.f, 0.f, 0.f};
    float wsum = 0.f;
    for (int i = k; i < deg; i += 16) {
        int p = start + i;
        int s = srcc[p];
        float lg = a2s[s] + ad + ae2c[p];
        lg = lg > 0.f ? lg : NEG_SLOPE * lg;
        float w = __expf(lg);
        float4 xv = *(const float4*)(xh2 + (size_t)s * 16 + l * 4);
        acc.x += w * xv.x; acc.y += w * xv.y; acc.z += w * xv.z; acc.w += w * xv.w;
        wsum += w;
    }
#pragma unroll
    for (int m = 4; m < 64; m <<= 1) {
        acc.x += __shfl_xor(acc.x, m); acc.y += __shfl_xor(acc.y, m);
        acc.z += __shfl_xor(acc.z, m); acc.w += __shfl_xor(acc.w, m);
        wsum += __shfl_xor(wsum, m);
    }
    float inv = 1.f / (wsum + 1e-16f);
    float4 b = *(const float4*)(b2 + l * 4);
    float4 lo;
    lo.x = acc.x * inv + b.x; lo.y = acc.y * inv + b.y;
    lo.z = acc.z * inv + b.z; lo.w = acc.w * inv + b.w;
    float mx = fmaxf(fmaxf(lo.x, lo.y), fmaxf(lo.z, lo.w));
    mx = fmaxf(mx, __shfl_xor(mx, 1)); mx = fmaxf(mx, __shfl_xor(mx, 2));
    float ex = __expf(lo.x - mx) + __expf(lo.y - mx) + __expf(lo.z - mx) + __expf(lo.w - mx);
    ex += __shfl_xor(ex, 1); ex += __shfl_xor(ex, 2);
    float ls = mx + __logf(ex);
    if (t < 4) {
        float4 r = {lo.x - ls, lo.y - ls, lo.z - ls, lo.w - ls};
        *(float4*)(out + (size_t)n * 16 + l * 4) = r;
    }
}

extern "C" void kernel_launch(void* const* d_in, const int* in_sizes, int n_in,
                              void* d_out, int out_size, void* d_ws, size_t ws_size,
                              hipStream_t stream) {
    const float* x     = (const float*)d_in[0];
    const int*   ei    = (const int*)d_in[1];
    const float* ea    = (const float*)d_in[2];
    const float* W1    = (const float*)d_in[3];
    const float* attS1 = (const float*)d_in[4];
    const float* attD1 = (const float*)d_in[5];
    const float* We1   = (const float*)d_in[6];
    const float* attE1 = (const float*)d_in[7];
    const float* b1    = (const float*)d_in[8];
    const float* W2    = (const float*)d_in[9];
    const float* attS2 = (const float*)d_in[10];
    const float* attD2 = (const float*)d_in[11];
    const float* We2   = (const float*)d_in[12];
    const float* attE2 = (const float*)d_in[13];
    const float* b2    = (const float*)d_in[14];
    float* out = (float*)d_out;
    const int* src = ei;
    const int* dst = ei + N_EDGES;

    char* p = (char*)d_ws;
    auto alloc = [&](size_t bytes) { char* r = p; p += (bytes + 255) & ~(size_t)255; return r; };
    __hip_bfloat16* xh1b = (__hip_bfloat16*)alloc((size_t)N_NODES * 128 * 2);  // 25.6 MB
    float* h1       = (float*)alloc((size_t)N_NODES * 128 * 4);                // 51.2 MB
    float* ew1c     = (float*)alloc((size_t)N_EDGES * 8 * 4);                  // 51.2 MB
    float* ae2c     = (float*)alloc((size_t)N_EDGES * 4);                      // 6.4 MB
    int*   srcc     = (int*)alloc((size_t)N_EDGES * 4);                        // 6.4 MB
    int4*  pes      = (int4*)alloc((size_t)N_EDGES * 16);                      // 25.6 MB
    float* xh2      = (float*)alloc((size_t)N_NODES * 16 * 4);                 // 6.4 MB
    float* a2s      = (float*)alloc((size_t)N_NODES * 4);
    float* a2d      = (float*)alloc((size_t)N_NODES * 4);
    float* a1s      = (float*)alloc((size_t)N_NODES * 8 * 4);
    float* a1d      = (float*)alloc((size_t)N_NODES * 8 * 4);
    int*   count    = (int*)alloc((size_t)N_NODES * 4);
    int*   cursor   = (int*)alloc((size_t)N_NODES * 4);   // contiguous after count
    int*   offs     = (int*)alloc((size_t)(N_NODES + 1) * 4);
    int*   partials = (int*)alloc(1024 * 4);
    float* M1       = (float*)alloc(128 * 4);
    float* M2       = (float*)alloc(64 * 4);
    if ((size_t)(p - (char*)d_ws) > ws_size) return;  // workspace too small — fail visibly

    const int nb_scan = (N_NODES + 255) / 256;  // 391

    hipMemsetAsync(count, 0, (size_t)2 * N_NODES * 4 + 256, stream);  // count + cursor
    k_pre<<<1, 192, 0, stream>>>(We1, attE1, We2, attE2, M1, M2);
    k_gemm1<<<(N_NODES + 127) / 128, 256, 0, stream>>>(x, W1, attS1, attD1, xh1b, a1s, a1d);
    k_hist<<<(N_EDGES + 255) / 256, 256, 0, stream>>>(dst, count);
    k_scan1<<<nb_scan, 256, 0, stream>>>(count, offs, partials);
    k_scan2<<<1, 512, 0, stream>>>(partials, nb_scan);
    k_scan3<<<nb_scan, 256, 0, stream>>>(offs, partials);
    k_scatter<<<N_EDGES / 256, 256, 0, stream>>>(src, dst, offs, cursor, pes);
    k_attn<<<N_EDGES / 256, 256, 0, stream>>>(pes, ea, M1, M2, a1s, a1d,
                                              ew1c, ae2c, srcc);
    k_agg1<<<N_NODES, 128, 0, stream>>>(srcc, ew1c, xh1b, offs, count, b1, h1);
    k_gemm2<<<N_NODES / 16, 256, 0, stream>>>(h1, W2, attS2, attD2, xh2, a2s, a2d);
    k_agg2<<<N_NODES, 64, 0, stream>>>(srcc, ae2c, a2s, a2d, xh2, offs, count, b2, out);
}

// Round 8
// 606.908 us; speedup vs baseline: 1.0671x; 1.0132x over previous
//
#include <hip/hip_runtime.h>
#include <hip/hip_bf16.h>

#define N_NODES 100000
#define N_EDGES 1600000
#define NEG_SLOPE 0.2f
#define LDS_STRIDE 132

typedef __attribute__((ext_vector_type(8))) short short8;
typedef __attribute__((ext_vector_type(4))) short short4v;
typedef __attribute__((ext_vector_type(4))) float floatx4;

__device__ inline short f2bf(float f) {
    __hip_bfloat16 h = __float2bfloat16(f);
    return *reinterpret_cast<short*>(&h);
}
__device__ inline float bf2f(unsigned short u) {
    union { unsigned int i; float f; } z; z.i = ((unsigned int)u) << 16; return z.f;
}

// ---------------- precompute M1[16][8], M2[16] ----------------
__global__ void k_pre(const float* __restrict__ We1, const float* __restrict__ attE1,
                      const float* __restrict__ We2, const float* __restrict__ attE2,
                      float* __restrict__ M1, float* __restrict__ M2) {
    int t = threadIdx.x;
    if (t < 128) {
        int d = t >> 3, h = t & 7;
        float s = 0.f;
        for (int c = 0; c < 16; ++c) s += We1[d * 128 + h * 16 + c] * attE1[h * 16 + c];
        M1[d * 8 + h] = s;   // layout [d][h]
    } else if (t < 144) {
        int d = t - 128;
        float s = 0.f;
        for (int c = 0; c < 16; ++c) s += We2[d * 16 + c] * attE2[c];
        M2[d] = s;
    }
}

// ---------------- GEMM1 via bf16 MFMA: 128 rows/block, packed staging ----------------
__global__ __launch_bounds__(256) void k_gemm1(
    const float* __restrict__ x, const float* __restrict__ W1,
    const float* __restrict__ attS, const float* __restrict__ attD,
    __hip_bfloat16* __restrict__ xh1b, float* __restrict__ a1s, float* __restrict__ a1d) {
    __shared__ short ldsW[128 * LDS_STRIDE];   // W1^T bf16 [n][k]
    __shared__ short ldsO[64 * LDS_STRIDE];    // out-tile staging
    int t = threadIdx.x;
    unsigned int* ldsW32 = (unsigned int*)ldsW;
    for (int u = t; u < 2048; u += 256) {
        int kp = u >> 5;            // k-pair 0..63
        int n4 = (u & 31) * 4;
        float4 a = *(const float4*)(W1 + (size_t)(2 * kp) * 128 + n4);
        float4 b = *(const float4*)(W1 + (size_t)(2 * kp + 1) * 128 + n4);
        ldsW32[(n4 + 0) * 66 + kp] =
            (unsigned int)(unsigned short)f2bf(a.x) | ((unsigned int)(unsigned short)f2bf(b.x) << 16);
        ldsW32[(n4 + 1) * 66 + kp] =
            (unsigned int)(unsigned short)f2bf(a.y) | ((unsigned int)(unsigned short)f2bf(b.y) << 16);
        ldsW32[(n4 + 2) * 66 + kp] =
            (unsigned int)(unsigned short)f2bf(a.z) | ((unsigned int)(unsigned short)f2bf(b.z) << 16);
        ldsW32[(n4 + 3) * 66 + kp] =
            (unsigned int)(unsigned short)f2bf(a.w) | ((unsigned int)(unsigned short)f2bf(b.w) << 16);
    }
    __syncthreads();
    int w = t >> 6, l = t & 63;
    int q = l >> 4, m = l & 15;
#pragma unroll
    for (int rt = 0; rt < 2; ++rt) {
        int row = blockIdx.x * 128 + rt * 64 + w * 16 + m;
        int rowc = row < N_NODES ? row : 0;
        floatx4 acc[8];
#pragma unroll
        for (int nt = 0; nt < 8; ++nt) acc[nt] = (floatx4){0.f, 0.f, 0.f, 0.f};
#pragma unroll
        for (int KK = 0; KK < 4; ++KK) {
            int k0 = KK * 32 + q * 8;
            float4 alo = *(const float4*)(x + (size_t)rowc * 128 + k0);
            float4 ahi = *(const float4*)(x + (size_t)rowc * 128 + k0 + 4);
            short8 a = {f2bf(alo.x), f2bf(alo.y), f2bf(alo.z), f2bf(alo.w),
                        f2bf(ahi.x), f2bf(ahi.y), f2bf(ahi.z), f2bf(ahi.w)};
#pragma unroll
            for (int nt = 0; nt < 8; ++nt) {
                const short* bp = &ldsW[(nt * 16 + m) * LDS_STRIDE + k0];
                short4v blo = *(const short4v*)bp;
                short4v bhi = *(const short4v*)(bp + 4);
                short8 b = {blo.x, blo.y, blo.z, blo.w, bhi.x, bhi.y, bhi.z, bhi.w};
                acc[nt] = __builtin_amdgcn_mfma_f32_16x16x32_bf16(a, b, acc[nt], 0, 0, 0);
            }
        }
        int rb = blockIdx.x * 128 + rt * 64 + w * 16 + q * 4;
#pragma unroll
        for (int nt = 0; nt < 8; ++nt) {
            float aS = attS[nt * 16 + m], aD = attD[nt * 16 + m];
            float p0 = acc[nt][0] * aS, p1 = acc[nt][1] * aS, p2 = acc[nt][2] * aS, p3 = acc[nt][3] * aS;
            float d0 = acc[nt][0] * aD, d1 = acc[nt][1] * aD, d2 = acc[nt][2] * aD, d3 = acc[nt][3] * aD;
            for (int dd = 1; dd < 16; dd <<= 1) {
                p0 += __shfl_xor(p0, dd); p1 += __shfl_xor(p1, dd);
                p2 += __shfl_xor(p2, dd); p3 += __shfl_xor(p3, dd);
                d0 += __shfl_xor(d0, dd); d1 += __shfl_xor(d1, dd);
                d2 += __shfl_xor(d2, dd); d3 += __shfl_xor(d3, dd);
            }
            if (m == 0) {
                if (rb + 0 < N_NODES) { a1s[(size_t)(rb+0)*8+nt] = p0; a1d[(size_t)(rb+0)*8+nt] = d0; }
                if (rb + 1 < N_NODES) { a1s[(size_t)(rb+1)*8+nt] = p1; a1d[(size_t)(rb+1)*8+nt] = d1; }
                if (rb + 2 < N_NODES) { a1s[(size_t)(rb+2)*8+nt] = p2; a1d[(size_t)(rb+2)*8+nt] = d2; }
                if (rb + 3 < N_NODES) { a1s[(size_t)(rb+3)*8+nt] = p3; a1d[(size_t)(rb+3)*8+nt] = d3; }
            }
        }
#pragma unroll
        for (int nt = 0; nt < 8; ++nt) {
#pragma unroll
            for (int r = 0; r < 4; ++r)
                ldsO[(w * 16 + q * 4 + r) * LDS_STRIDE + nt * 16 + m] = f2bf(acc[nt][r]);
        }
        __syncthreads();
        int r2 = t >> 2, c2 = (t & 3) * 32;
        int gr = blockIdx.x * 128 + rt * 64 + r2;
        if (gr < N_NODES) {
            short* gp = (short*)(xh1b + (size_t)gr * 128 + c2);
#pragma unroll
            for (int i = 0; i < 8; ++i)
                *(short4v*)(gp + i * 4) = *(const short4v*)&ldsO[r2 * LDS_STRIDE + c2 + i * 4];
        }
        __syncthreads();
    }
}

// ---------------- CSR build: 4 edges/thread batched atomics ----------------
__global__ __launch_bounds__(256) void k_hist(const int* __restrict__ dst, int* __restrict__ count) {
    int base = blockIdx.x * 1024 + threadIdx.x;
#pragma unroll
    for (int k = 0; k < 4; ++k) {
        int i = base + k * 256;
        if (i < N_EDGES) atomicAdd(&count[dst[i]], 1);
    }
}

__global__ __launch_bounds__(256) void k_scan1(const int* __restrict__ count,
                                               int* __restrict__ offs, int* __restrict__ partials) {
    __shared__ int s[256];
    int t = threadIdx.x;
    int i = blockIdx.x * 256 + t;
    int v = (i < N_NODES) ? count[i] : 0;
    s[t] = v; __syncthreads();
    for (int off = 1; off < 256; off <<= 1) {
        int add = (t >= off) ? s[t - off] : 0;
        __syncthreads();
        s[t] += add; __syncthreads();
    }
    if (i < N_NODES) offs[i] = s[t] - v;
    if (t == 255) partials[blockIdx.x] = s[255];
}

__global__ __launch_bounds__(512) void k_scan2(int* __restrict__ partials, int nb) {
    __shared__ int s[512];
    int t = threadIdx.x;
    int v = (t < nb) ? partials[t] : 0;
    s[t] = v; __syncthreads();
    for (int off = 1; off < 512; off <<= 1) {
        int add = (t >= off) ? s[t - off] : 0;
        __syncthreads();
        s[t] += add; __syncthreads();
    }
    if (t < nb) partials[t] = s[t] - v;
}

__global__ void k_scan3(int* __restrict__ offs, const int* __restrict__ partials) {
    int i = blockIdx.x * 256 + threadIdx.x;
    if (i < N_NODES) offs[i] += partials[blockIdx.x];
}

// ---------------- k_scatter: 4 edges/thread, batched atomics + 8B scatters ----------------
__global__ __launch_bounds__(256) void k_scatter(
    const int* __restrict__ src, const int* __restrict__ dst, const int* __restrict__ offs,
    int* __restrict__ cursor, int2* __restrict__ pes) {
    int base = blockIdx.x * 1024 + threadIdx.x;
    int e[4], d[4], s[4];
#pragma unroll
    for (int k = 0; k < 4; ++k) {
        e[k] = base + k * 256;
        int ec = e[k] < N_EDGES ? e[k] : 0;
        d[k] = dst[ec];
        s[k] = src[ec];
    }
    int p[4];
#pragma unroll
    for (int k = 0; k < 4; ++k) {
        p[k] = (e[k] < N_EDGES) ? offs[d[k]] + atomicAdd(&cursor[d[k]], 1) : -1;
    }
#pragma unroll
    for (int k = 0; k < 4; ++k) {
        if (p[k] >= 0) {
            int2 v; v.x = e[k]; v.y = s[k];
            pes[p[k]] = v;
        }
    }
}

// ---------------- k_fill: dstc[p] = owning node (CSR segment id) ----------------
__global__ __launch_bounds__(256) void k_fill(
    const int* __restrict__ offs, const int* __restrict__ count, int* __restrict__ dstc) {
    int n = blockIdx.x * 256 + threadIdx.x;
    if (n >= N_NODES) return;
    int s = offs[n], e = s + count[n];
    for (int i = s; i < e; ++i) dstc[i] = n;
}

// ---------------- k_attn: CSR-order; only random access is the ea line gather ----------------
__global__ __launch_bounds__(256) void k_attn(
    const int2* __restrict__ pes, const int* __restrict__ dstc,
    const float* __restrict__ ea, const float* __restrict__ M1, const float* __restrict__ M2,
    const float* __restrict__ a1s, const float* __restrict__ a1d,
    float* __restrict__ ew1c, float* __restrict__ ae2c, int* __restrict__ srcc) {
    __shared__ float M1s[128], M2s[16];
    int t = threadIdx.x;
    if (t < 128) M1s[t] = M1[t];
    if (t >= 128 && t < 144) M2s[t - 128] = M2[t - 128];
    __syncthreads();
    int p = blockIdx.x * 256 + t;
    int2 es = pes[p];
    int e = es.x, s = es.y;
    int d = dstc[p];                      // near-uniform across adjacent lanes -> broadcast
    float eav[16];
#pragma unroll
    for (int qq = 0; qq < 4; ++qq) {
        float4 v = *(const float4*)(ea + (size_t)e * 16 + qq * 4);
        eav[qq * 4] = v.x; eav[qq * 4 + 1] = v.y; eav[qq * 4 + 2] = v.z; eav[qq * 4 + 3] = v.w;
    }
    float ae1[8];
#pragma unroll
    for (int h = 0; h < 8; ++h) ae1[h] = 0.f;
#pragma unroll
    for (int dd = 0; dd < 16; ++dd) {
#pragma unroll
        for (int h = 0; h < 8; ++h) ae1[h] += eav[dd] * M1s[dd * 8 + h];
    }
    float aes = 0.f;
#pragma unroll
    for (int dd = 0; dd < 16; ++dd) aes += eav[dd] * M2s[dd];
    float4 s0 = *(const float4*)(a1s + (size_t)s * 8);
    float4 s1 = *(const float4*)(a1s + (size_t)s * 8 + 4);
    float4 d0 = *(const float4*)(a1d + (size_t)d * 8);
    float4 d1 = *(const float4*)(a1d + (size_t)d * 8 + 4);
    float as_[8] = {s0.x, s0.y, s0.z, s0.w, s1.x, s1.y, s1.z, s1.w};
    float ad_[8] = {d0.x, d0.y, d0.z, d0.w, d1.x, d1.y, d1.z, d1.w};
    float ew[8];
#pragma unroll
    for (int h = 0; h < 8; ++h) {
        float v = as_[h] + ad_[h] + ae1[h];
        v = v > 0.f ? v : NEG_SLOPE * v;
        ew[h] = __expf(v);
    }
    float4 w0 = {ew[0], ew[1], ew[2], ew[3]};
    float4 w1 = {ew[4], ew[5], ew[6], ew[7]};
    *(float4*)(ew1c + (size_t)p * 8) = w0;
    *(float4*)(ew1c + (size_t)p * 8 + 4) = w1;
    ae2c[p] = aes;
    srcc[p] = s;
}

// ---------------- layer-1 aggregation: 2-way unrolled bf16 row gathers ----------------
__global__ __launch_bounds__(128) void k_agg1(
    const int* __restrict__ srcc, const float* __restrict__ ew1c,
    const __hip_bfloat16* __restrict__ xh1b, const int* __restrict__ offs,
    const int* __restrict__ count, const float* __restrict__ b1, float* __restrict__ h1) {
    __shared__ float4 racc[32];
    __shared__ float rw[32];
    int n = blockIdx.x;
    int t = threadIdx.x;
    int j = t & 31, k = t >> 5;
    int hh = j >> 2;
    int start = offs[n], deg = count[n];
    float4 acc = {0.f, 0.f, 0.f, 0.f};
    float wsum = 0.f;
    for (int i = k; i < deg; i += 8) {
        int p0 = start + i;
        int s0 = srcc[p0];
        float w0 = ew1c[(size_t)p0 * 8 + hh];
        int i1 = i + 4;
        int s1 = 0; float w1 = 0.f;
        if (i1 < deg) {
            int p1 = start + i1;
            s1 = srcc[p1];
            w1 = ew1c[(size_t)p1 * 8 + hh];
        }
        uint2 xv0 = *(const uint2*)((const char*)xh1b + (size_t)s0 * 256 + j * 8);
        uint2 xv1 = *(const uint2*)((const char*)xh1b + (size_t)s1 * 256 + j * 8);
        acc.x += w0 * bf2f((unsigned short)(xv0.x & 0xffff));
        acc.y += w0 * bf2f((unsigned short)(xv0.x >> 16));
        acc.z += w0 * bf2f((unsigned short)(xv0.y & 0xffff));
        acc.w += w0 * bf2f((unsigned short)(xv0.y >> 16));
        acc.x += w1 * bf2f((unsigned short)(xv1.x & 0xffff));
        acc.y += w1 * bf2f((unsigned short)(xv1.x >> 16));
        acc.z += w1 * bf2f((unsigned short)(xv1.y & 0xffff));
        acc.w += w1 * bf2f((unsigned short)(xv1.y >> 16));
        wsum += w0 + w1;
    }
    acc.x += __shfl_xor(acc.x, 32); acc.y += __shfl_xor(acc.y, 32);
    acc.z += __shfl_xor(acc.z, 32); acc.w += __shfl_xor(acc.w, 32);
    wsum += __shfl_xor(wsum, 32);
    if (t >= 64 && t < 96) { racc[j] = acc; rw[j] = wsum; }
    __syncthreads();
    if (t < 32) {
        float4 o = racc[j];
        acc.x += o.x; acc.y += o.y; acc.z += o.z; acc.w += o.w;
        wsum += rw[j];
        float inv = 1.f / (wsum + 1e-16f);
        float4 b = *(const float4*)(b1 + j * 4);
        float4 r;
        r.x = acc.x * inv + b.x; r.y = acc.y * inv + b.y;
        r.z = acc.z * inv + b.z; r.w = acc.w * inv + b.w;
        r.x = r.x > 0.f ? r.x : __expf(r.x) - 1.f;
        r.y = r.y > 0.f ? r.y : __expf(r.y) - 1.f;
        r.z = r.z > 0.f ? r.z : __expf(r.z) - 1.f;
        r.w = r.w > 0.f ? r.w : __expf(r.w) - 1.f;
        *(float4*)(h1 + (size_t)n * 128 + j * 4) = r;
    }
}

// ---------------- GEMM2: xh2 = h1 @ W2, plus a2s/a2d ----------------
__global__ __launch_bounds__(256) void k_gemm2(
    const float* __restrict__ h1, const float* __restrict__ W2,
    const float* __restrict__ attS, const float* __restrict__ attD,
    float* __restrict__ xh2, float* __restrict__ a2s, float* __restrict__ a2d) {
    __shared__ float W2s[128 * 16];
    __shared__ float hs[16 * 132];
    int t = threadIdx.x;
    for (int i = t * 4; i < 2048; i += 1024)
        *(float4*)(W2s + i) = *(const float4*)(W2 + i);
    size_t base = (size_t)blockIdx.x * 16 * 128;
    for (int i = t * 4; i < 2048; i += 1024) {
        float4 v = *(const float4*)(h1 + base + i);
        int r = i >> 7, k = i & 127;
        float* dstp = hs + r * 132 + k;
        dstp[0] = v.x; dstp[1] = v.y; dstp[2] = v.z; dstp[3] = v.w;
    }
    __syncthreads();
    int r = t >> 4, c = t & 15;
    float acc = 0.f;
#pragma unroll 4
    for (int k = 0; k < 128; ++k) acc += hs[r * 132 + k] * W2s[k * 16 + c];
    int row = blockIdx.x * 16 + r;
    xh2[(size_t)row * 16 + c] = acc;
    float ps = acc * attS[c], pd = acc * attD[c];
#pragma unroll
    for (int m = 1; m < 16; m <<= 1) { ps += __shfl_xor(ps, m); pd += __shfl_xor(pd, m); }
    if (c == 0) { a2s[row] = ps; a2d[row] = pd; }
}

// ---------------- layer-2 aggregation + bias + log_softmax ----------------
__global__ __launch_bounds__(64) void k_agg2(
    const int* __restrict__ srcc, const float* __restrict__ ae2c,
    const float* __restrict__ a2s, const float* __restrict__ a2d, const float* __restrict__ xh2,
    const int* __restrict__ offs, const int* __restrict__ count,
    const float* __restrict__ b2, float* __restrict__ out) {
    int n = blockIdx.x;
    int t = threadIdx.x;
    int l = t & 3, k = t >> 2;
    int start = offs[n], deg = count[n];
    float ad = a2d[n];
    float4 acc = {0.f, 0.f, 0.f, 0.f};
    float wsum = 0.f;
    for (int i = k; i < deg; i += 16) {
        int p = start + i;
        int s = srcc[p];
        float lg = a2s[s] + ad + ae2c[p];
        lg = lg > 0.f ? lg : NEG_SLOPE * lg;
        float w = __expf(lg);
        float4 xv = *(const float4*)(xh2 + (size_t)s * 16 + l * 4);
        acc.x += w * xv.x; acc.y += w * xv.y; acc.z += w * xv.z; acc.w += w * xv.w;
        wsum += w;
    }
#pragma unroll
    for (int m = 4; m < 64; m <<= 1) {
        acc.x += __shfl_xor(acc.x, m); acc.y += __shfl_xor(acc.y, m);
        acc.z += __shfl_xor(acc.z, m); acc.w += __shfl_xor(acc.w, m);
        wsum += __shfl_xor(wsum, m);
    }
    float inv = 1.f / (wsum + 1e-16f);
    float4 b = *(const float4*)(b2 + l * 4);
    float4 lo;
    lo.x = acc.x * inv + b.x; lo.y = acc.y * inv + b.y;
    lo.z = acc.z * inv + b.z; lo.w = acc.w * inv + b.w;
    float mx = fmaxf(fmaxf(lo.x, lo.y), fmaxf(lo.z, lo.w));
    mx = fmaxf(mx, __shfl_xor(mx, 1)); mx = fmaxf(mx, __shfl_xor(mx, 2));
    float ex = __expf(lo.x - mx) + __expf(lo.y - mx) + __expf(lo.z - mx) + __expf(lo.w - mx);
    ex += __shfl_xor(ex, 1); ex += __shfl_xor(ex, 2);
    float ls = mx + __logf(ex);
    if (t < 4) {
        float4 r = {lo.x - ls, lo.y - ls, lo.z - ls, lo.w - ls};
        *(float4*)(out + (size_t)n * 16 + l * 4) = r;
    }
}

extern "C" void kernel_launch(void* const* d_in, const int* in_sizes, int n_in,
                              void* d_out, int out_size, void* d_ws, size_t ws_size,
                              hipStream_t stream) {
    const float* x     = (const float*)d_in[0];
    const int*   ei    = (const int*)d_in[1];
    const float* ea    = (const float*)d_in[2];
    const float* W1    = (const float*)d_in[3];
    const float* attS1 = (const float*)d_in[4];
    const float* attD1 = (const float*)d_in[5];
    const float* We1   = (const float*)d_in[6];
    const float* attE1 = (const float*)d_in[7];
    const float* b1    = (const float*)d_in[8];
    const float* W2    = (const float*)d_in[9];
    const float* attS2 = (const float*)d_in[10];
    const float* attD2 = (const float*)d_in[11];
    const float* We2   = (const float*)d_in[12];
    const float* attE2 = (const float*)d_in[13];
    const float* b2    = (const float*)d_in[14];
    float* out = (float*)d_out;
    const int* src = ei;
    const int* dst = ei + N_EDGES;

    char* p = (char*)d_ws;
    auto alloc = [&](size_t bytes) { char* r = p; p += (bytes + 255) & ~(size_t)255; return r; };
    __hip_bfloat16* xh1b = (__hip_bfloat16*)alloc((size_t)N_NODES * 128 * 2);  // 25.6 MB
    float* h1       = (float*)alloc((size_t)N_NODES * 128 * 4);                // 51.2 MB
    float* ew1c     = (float*)alloc((size_t)N_EDGES * 8 * 4);                  // 51.2 MB
    float* ae2c     = (float*)alloc((size_t)N_EDGES * 4);                      // 6.4 MB
    int*   srcc     = (int*)alloc((size_t)N_EDGES * 4);                        // 6.4 MB
    int2*  pes      = (int2*)alloc((size_t)N_EDGES * 8);                       // 12.8 MB
    int*   dstc     = (int*)alloc((size_t)N_EDGES * 4);                        // 6.4 MB
    float* xh2      = (float*)alloc((size_t)N_NODES * 16 * 4);                 // 6.4 MB
    float* a2s      = (float*)alloc((size_t)N_NODES * 4);
    float* a2d      = (float*)alloc((size_t)N_NODES * 4);
    float* a1s      = (float*)alloc((size_t)N_NODES * 8 * 4);
    float* a1d      = (float*)alloc((size_t)N_NODES * 8 * 4);
    int*   count    = (int*)alloc((size_t)N_NODES * 4);
    int*   cursor   = (int*)alloc((size_t)N_NODES * 4);   // contiguous after count
    int*   offs     = (int*)alloc((size_t)(N_NODES + 1) * 4);
    int*   partials = (int*)alloc(1024 * 4);
    float* M1       = (float*)alloc(128 * 4);
    float* M2       = (float*)alloc(64 * 4);
    if ((size_t)(p - (char*)d_ws) > ws_size) return;  // workspace too small — fail visibly

    const int nb_scan = (N_NODES + 255) / 256;  // 391
    const int nb_edge4 = (N_EDGES + 1023) / 1024;  // 1563

    hipMemsetAsync(count, 0, (size_t)2 * N_NODES * 4 + 256, stream);  // count + cursor
    k_pre<<<1, 192, 0, stream>>>(We1, attE1, We2, attE2, M1, M2);
    k_gemm1<<<(N_NODES + 127) / 128, 256, 0, stream>>>(x, W1, attS1, attD1, xh1b, a1s, a1d);
    k_hist<<<nb_edge4, 256, 0, stream>>>(dst, count);
    k_scan1<<<nb_scan, 256, 0, stream>>>(count, offs, partials);
    k_scan2<<<1, 512, 0, stream>>>(partials, nb_scan);
    k_scan3<<<nb_scan, 256, 0, stream>>>(offs, partials);
    k_scatter<<<nb_edge4, 256, 0, stream>>>(src, dst, offs, cursor, pes);
    k_fill<<<nb_scan, 256, 0, stream>>>(offs, count, dstc);
    k_attn<<<N_EDGES / 256, 256, 0, stream>>>(pes, dstc, ea, M1, M2, a1s, a1d,
                                              ew1c, ae2c, srcc);
    k_agg1<<<N_NODES, 128, 0, stream>>>(srcc, ew1c, xh1b, offs, count, b1, h1);
    k_gemm2<<<N_NODES / 16, 256, 0, stream>>>(h1, W2, attS2, attD2, xh2, a2s, a2d);
    k_agg2<<<N_NODES, 64, 0, stream>>>(srcc, ae2c, a2s, a2d, xh2, offs, count, b2, out);
}